// Round 13
// baseline (344.101 us; speedup 1.0000x reference)
//
#include <hip/hip_runtime.h>
#include <hip/hip_bf16.h>

// 3-layer GAT: N=50000, E=1.6M (+implicit self loops), 13->128->128->5, log_softmax.
// f32 in/out (runtime-verified), edge_index width runtime-detected.
// Round 13: (1) W2 pre-packed to bf16^T once (gemm_mfma staging = aligned b128,
// no per-block conversion / bank conflicts); (2) agg128 split into 2 half-range
// dispatches (perf-neutral, lowers top-5 cutoff to surface tail kernels);
// (3) agg inner loop reverted to round-11 variant (measured faster).

#define LEAKY(e) ((e) > 0.f ? (e) : 0.2f * (e))
__device__ inline float clamp30(float e) { return fminf(fmaxf(e, -30.f), 30.f); }
__device__ inline float expc(float e) { return __expf(clamp30(LEAKY(e))); }

__device__ inline float ldany(const void* p, int bf, int i) {
    return bf ? __bfloat162float(((const __hip_bfloat16*)p)[i])
              : ((const float*)p)[i];
}
__device__ inline int ldidx(const void* p, int i64, long long i) {
    return i64 ? (int)(((const unsigned int*)p)[2 * i])
               : ((const int*)p)[i];
}

__device__ inline float bflo(unsigned int w) { return __uint_as_float(w << 16); }
__device__ inline float bfhi(unsigned int w) { return __uint_as_float(w & 0xffff0000u); }
__device__ inline unsigned short bfbits(float a) {
    __hip_bfloat16 x = __float2bfloat16(a);
    unsigned short u; __builtin_memcpy(&u, &x, 2); return u;
}
__device__ inline unsigned int packbf(float a, float b) {
    return (unsigned int)bfbits(a) | ((unsigned int)bfbits(b) << 16);
}

typedef __attribute__((ext_vector_type(8))) short short8;
typedef __attribute__((ext_vector_type(4))) float f32x4;

__global__ void detect_kernel(const void* W1, const void* ei, int* flags) {
    if (threadIdx.x == 0 && blockIdx.x == 0) {
        const unsigned int* w = (const unsigned int*)W1;
        int c = 0;
        for (int i = 0; i < 64; i++) {
            unsigned int e = (w[i] >> 7) & 0xFFu;
            if (e >= 0x70u && e <= 0x7Fu) c++;
        }
        flags[0] = (c >= 32) ? 1 : 0;
        const unsigned int* q = (const unsigned int*)ei;
        int z = 0;
        for (int i = 0; i < 64; i++)
            if (q[2 * i + 1] == 0u) z++;
        flags[1] = (z >= 32) ? 1 : 0;
    }
}

// ================= CSR build (contention-free chain) =================

__global__ __launch_bounds__(256) void sortA_hist(
    const void* __restrict__ ei, const int* __restrict__ flags,
    int* __restrict__ blockHist, int E, int NBUK)
{
    __shared__ int hist[512];
    const int i64 = flags[1];
    const int tid = threadIdx.x, blk = blockIdx.x;
    for (int i = tid; i < NBUK; i += 256) hist[i] = 0;
    __syncthreads();
    const int chunk = (E + 255) / 256;
    const int e0 = blk * chunk, e1 = min(e0 + chunk, E);
    for (int t = e0 + tid; t < e1; t += 256) {
        int d = ldidx(ei, i64, (long long)E + t);
        atomicAdd(&hist[d >> 7], 1);
    }
    __syncthreads();
    for (int i = tid; i < NBUK; i += 256)
        blockHist[blk * NBUK + i] = hist[i];
}

__global__ __launch_bounds__(256) void sortB_prefix(
    int* __restrict__ blockHist, int* __restrict__ bucketBase, int NBUK)
{
    __shared__ int wt[4];
    __shared__ int wbase[4];
    const int b = blockIdx.x;
    const int tid = threadIdx.x, lane = tid & 63, wid = tid >> 6;
    int v = blockHist[tid * NBUK + b];
    int x = v;
#pragma unroll
    for (int o = 1; o < 64; o <<= 1) {
        int y = __shfl_up(x, o);
        if (lane >= o) x += y;
    }
    if (lane == 63) wt[wid] = x;
    __syncthreads();
    if (tid == 0) {
        int s = 0;
#pragma unroll
        for (int i = 0; i < 4; i++) { wbase[i] = s; s += wt[i]; }
        bucketBase[b] = s;
    }
    __syncthreads();
    blockHist[tid * NBUK + b] = x - v + wbase[wid];
}

__global__ __launch_bounds__(512) void sortB2_scan(
    int* __restrict__ bucketBase, int NBUK)
{
    __shared__ int wt[8];
    __shared__ int wbase[8];
    __shared__ int total_s;
    const int tid = threadIdx.x, lane = tid & 63, wid = tid >> 6;
    int v = (tid < NBUK) ? bucketBase[tid] : 0;
    int x = v;
#pragma unroll
    for (int o = 1; o < 64; o <<= 1) {
        int y = __shfl_up(x, o);
        if (lane >= o) x += y;
    }
    if (lane == 63) wt[wid] = x;
    __syncthreads();
    if (tid == 0) {
        int s = 0;
#pragma unroll
        for (int i = 0; i < 8; i++) { wbase[i] = s; s += wt[i]; }
        total_s = s;
    }
    __syncthreads();
    if (tid < NBUK) bucketBase[tid] = x - v + wbase[wid];
    if (tid == 0) bucketBase[NBUK] = total_s;
}

__global__ __launch_bounds__(256) void sortC_scatter(
    const void* __restrict__ ei, const int* __restrict__ flags,
    const int* __restrict__ blockHist, const int* __restrict__ bucketBase,
    unsigned int* __restrict__ pairbuf, int E, int NBUK)
{
    __shared__ int cur[512];
    const int i64 = flags[1];
    const int tid = threadIdx.x, blk = blockIdx.x;
    for (int i = tid; i < NBUK; i += 256)
        cur[i] = blockHist[blk * NBUK + i] + bucketBase[i];
    __syncthreads();
    const int chunk = (E + 255) / 256;
    const int e0 = blk * chunk, e1 = min(e0 + chunk, E);
    for (int t = e0 + tid; t < e1; t += 256) {
        int s = ldidx(ei, i64, t);
        int d = ldidx(ei, i64, (long long)E + t);
        int pos = atomicAdd(&cur[d >> 7], 1);
        pairbuf[pos] = ((unsigned int)(d & 127) << 16) | (unsigned int)s;
    }
}

__global__ __launch_bounds__(256) void sortD_bin(
    const unsigned int* __restrict__ pairbuf, const int* __restrict__ bucketBase,
    int* __restrict__ rowptr, unsigned short* __restrict__ ssrc, int N, int NBUK)
{
    __shared__ int cnt[128];
    __shared__ int cur2[128];
    __shared__ int wt1;
    const int b = blockIdx.x;
    const int tid = threadIdx.x, lane = tid & 63;
    const int e0 = bucketBase[b], e1 = bucketBase[b + 1];
    if (tid < 128) cnt[tid] = 0;
    __syncthreads();
    for (int i = e0 + tid; i < e1; i += 256)
        atomicAdd(&cnt[pairbuf[i] >> 16], 1);
    __syncthreads();
    if (tid < 128) {
        int v = cnt[tid];
        int x = v;
#pragma unroll
        for (int o = 1; o < 64; o <<= 1) {
            int y = __shfl_up(x, o);
            if (lane >= o) x += y;
        }
        if (tid == 63) wt1 = x;
        __syncthreads();
        if (tid >= 64) x += wt1;
        int pfx = x - v;
        cur2[tid] = pfx;
        int node = b * 128 + tid;
        if (node < N) rowptr[node] = e0 + pfx;
    } else {
        __syncthreads();
    }
    if (b == NBUK - 1 && tid == 0) rowptr[N] = e1;
    __syncthreads();
    for (int i = e0 + tid; i < e1; i += 256) {
        unsigned int w = pairbuf[i];
        int p = atomicAdd(&cur2[w >> 16], 1);
        ssrc[e0 + p] = (unsigned short)(w & 0xFFFFu);
    }
}

// ================= projection kernels =================

__global__ __launch_bounds__(256) void node_prep13(
    const void* __restrict__ xin, const void* __restrict__ Wg,
    const void* __restrict__ asg, const void* __restrict__ adg,
    const int* __restrict__ flags,
    unsigned int* __restrict__ h2, float* __restrict__ asrc,
    float* __restrict__ adst, int N)
{
    const int bf = flags[0];
    __shared__ float Wlds[13 * 128];
    for (int i = threadIdx.x; i < 13 * 128; i += 256)
        Wlds[i] = ldany(Wg, bf, i);
    __syncthreads();
    const int lane = threadIdx.x & 63;
    int wave = (blockIdx.x * 256 + threadIdx.x) >> 6;
    int nw = (gridDim.x * 256) >> 6;
    float a0 = ldany(asg, bf, 2 * lane), a1 = ldany(asg, bf, 2 * lane + 1);
    float d0 = ldany(adg, bf, 2 * lane), d1 = ldany(adg, bf, 2 * lane + 1);
    for (int n = wave; n < N; n += nw) {
        float x0 = (lane < 13) ? ldany(xin, bf, n * 13 + lane) : 0.f;
        float s0 = 0.f, s1 = 0.f;
#pragma unroll
        for (int k = 0; k < 13; k++) {
            float xv = __shfl(x0, k);
            s0 += xv * Wlds[k * 128 + 2 * lane];
            s1 += xv * Wlds[k * 128 + 2 * lane + 1];
        }
        float pa = s0 * a0 + s1 * a1;
        float pd = s0 * d0 + s1 * d1;
#pragma unroll
        for (int o = 32; o > 0; o >>= 1) {
            pa += __shfl_xor(pa, o);
            pd += __shfl_xor(pd, o);
        }
        if (lane == 0) { asrc[n] = pa; adst[n] = pd; }
        h2[(size_t)n * 64 + lane] = packbf(s0, s1);
    }
}

// One-time: W2 -> bf16 transpose (W2T[n][k]), 32 KB.
__global__ __launch_bounds__(128) void packW2T(
    const void* __restrict__ Wg, const int* __restrict__ flags,
    unsigned short* __restrict__ W2T)
{
    const int bf = flags[0];
    const int n = blockIdx.x;            // 128 blocks, one output row each
    const int k = threadIdx.x;           // 128 threads
    W2T[n * 128 + k] = bf ? ((const unsigned short*)Wg)[k * 128 + n]
                          : bfbits(((const float*)Wg)[k * 128 + n]);
}

// Layer 2 via MFMA bf16 (layouts verified m89/m91); B staged from pre-packed W2T.
__global__ __launch_bounds__(256) void gemm_mfma(
    const float* __restrict__ X, const unsigned short* __restrict__ W2T,
    const void* __restrict__ asg, const void* __restrict__ adg,
    const int* __restrict__ flags, unsigned int* __restrict__ h2,
    float* __restrict__ asrc, float* __restrict__ adst, int N)
{
    const int bf = flags[0];
    __shared__ unsigned short A_s[64 * 136];
    __shared__ unsigned short B_s[128 * 136];
    const int tid = threadIdx.x;
    const int nb0 = blockIdx.x * 64;

    // B: vectorized aligned staging (2048 x 16B)
#pragma unroll
    for (int it = 0; it < 8; it++) {
        int f = it * 256 + tid;               // 0..2047
        int n = f >> 4, kc = (f & 15) * 8;
        uint4 v = *(const uint4*)&W2T[n * 128 + kc];
        *(uint4*)&B_s[n * 136 + kc] = v;      // 272B row stride: 16B-aligned
    }
    // A: 64 x 128 f32 -> bf16 pairs
#pragma unroll
    for (int it = 0; it < 8; it++) {
        int f = it * 256 + tid;
        int n = f >> 5, g = f & 31;
        int node = min(nb0 + n, N - 1);
        float4 v = *(const float4*)&X[(size_t)node * 128 + g * 4];
        unsigned int* dst = (unsigned int*)&A_s[n * 136 + g * 4];
        dst[0] = packbf(v.x, v.y);
        dst[1] = packbf(v.z, v.w);
    }
    __syncthreads();

    const int wv = tid >> 6;
    const int lane = tid & 63;
    const int m = lane & 15, quad = lane >> 4;

    f32x4 acc[8];
#pragma unroll
    for (int c = 0; c < 8; c++) acc[c] = (f32x4){0.f, 0.f, 0.f, 0.f};

#pragma unroll
    for (int q = 0; q < 4; q++) {
        short8 a = *(const short8*)&A_s[(wv * 16 + m) * 136 + q * 32 + quad * 8];
#pragma unroll
        for (int c = 0; c < 8; c++) {
            short8 b = *(const short8*)&B_s[(c * 16 + m) * 136 + q * 32 + quad * 8];
            acc[c] = __builtin_amdgcn_mfma_f32_16x16x32_bf16(a, b, acc[c], 0, 0, 0);
        }
    }

    float asv[8], adv[8];
#pragma unroll
    for (int c = 0; c < 8; c++) {
        asv[c] = ldany(asg, bf, c * 16 + m);
        adv[c] = ldany(adg, bf, c * 16 + m);
    }
    unsigned short* h2u = (unsigned short*)h2;
#pragma unroll
    for (int reg = 0; reg < 4; reg++) {
        int node = nb0 + wv * 16 + quad * 4 + reg;
        float pa = 0.f, pd = 0.f;
#pragma unroll
        for (int c = 0; c < 8; c++) {
            float v = acc[c][reg];
            pa += v * asv[c];
            pd += v * adv[c];
            if (node < N) h2u[(size_t)node * 128 + c * 16 + m] = bfbits(v);
        }
#pragma unroll
        for (int o = 1; o < 16; o <<= 1) {
            pa += __shfl_xor(pa, o);
            pd += __shfl_xor(pd, o);
        }
        if (node < N && m == 0) { asrc[node] = pa; adst[node] = pd; }
    }
}

// Layer 3: thread-per-node; h3 padded to stride 8.
__global__ __launch_bounds__(256) void proj7(
    const float* __restrict__ X, const void* __restrict__ W3,
    const void* __restrict__ as3, const void* __restrict__ ad3,
    const int* __restrict__ flags, float* __restrict__ h3p,
    float* __restrict__ asrc, float* __restrict__ adst, int N)
{
    const int bf = flags[0];
    __shared__ float Wp[128 * 8];
    __shared__ float xs[256 * 33];
    const int tid = threadIdx.x;
    for (int i = tid; i < 128 * 8; i += 256) {
        int k = i >> 3, j = i & 7;
        float v = 0.f;
        if (j < 5) v = ldany(W3, bf, k * 5 + j);
        else if (j == 5) v = ldany(as3, bf, k);
        else if (j == 6) v = ldany(ad3, bf, k);
        Wp[i] = v;
    }
    const int nb0 = blockIdx.x * 256;
    float acc[7] = {0.f, 0.f, 0.f, 0.f, 0.f, 0.f, 0.f};
    for (int kc = 0; kc < 128; kc += 32) {
        __syncthreads();
#pragma unroll
        for (int it = 0; it < 32; it++) {
            int f = it * 256 + tid;
            int row = f >> 5, k = f & 31;
            int node = nb0 + row;
            xs[row * 33 + k] = (node < N) ? X[(size_t)node * 128 + kc + k] : 0.f;
        }
        __syncthreads();
#pragma unroll
        for (int k = 0; k < 32; k++) {
            float xv = xs[tid * 33 + k];
            float4 w0 = *(float4*)&Wp[(kc + k) * 8];
            float4 w1 = *(float4*)&Wp[(kc + k) * 8 + 4];
            acc[0] += xv * w0.x; acc[1] += xv * w0.y; acc[2] += xv * w0.z;
            acc[3] += xv * w0.w; acc[4] += xv * w1.x; acc[5] += xv * w1.y;
            acc[6] += xv * w1.z;
        }
    }
    int node = nb0 + tid;
    if (node < N) {
        float4 o0 = {acc[0], acc[1], acc[2], acc[3]};
        float4 o1 = {acc[4], 0.f, 0.f, 0.f};
        *(float4*)&h3p[(size_t)node * 8] = o0;
        *(float4*)&h3p[(size_t)node * 8 + 4] = o1;
        asrc[node] = acc[5];
        adst[node] = acc[6];
    }
}

// ================= aggregation kernels =================

__device__ inline int rdl(int v, int j) { return __builtin_amdgcn_readlane(v, j); }
__device__ inline float rdlf(float v, int j) {
    return __uint_as_float((unsigned int)__builtin_amdgcn_readlane((int)__float_as_uint(v), j));
}

// Half-range dispatch: nodes [nStart, nEnd).
__global__ __launch_bounds__(256) void agg_fused128(
    const int* __restrict__ rowptr, const unsigned short* __restrict__ ssrc,
    const unsigned int* __restrict__ h2, const float* __restrict__ asrc,
    const float* __restrict__ adst, const void* __restrict__ bias,
    const int* __restrict__ flags, float* __restrict__ feat, int nStart, int nEnd)
{
    const int bf = flags[0];
    const int lane = threadIdx.x & 63;
    int wave = (blockIdx.x * 256 + threadIdx.x) >> 6;
    int nw = (gridDim.x * 256) >> 6;
    const float bx = ldany(bias, bf, 2 * lane);
    const float by = ldany(bias, bf, 2 * lane + 1);
    const unsigned ul = (unsigned)lane;

    for (int n = nStart + wave; n < nEnd; n += nw) {
        float ad = adst[n];
        float wself = expc(asrc[n] + ad);
        unsigned int hw = h2[((unsigned)n << 6) | ul];
        float accx = wself * bflo(hw), accy = wself * bfhi(hw);
        float wpart = (lane == 0) ? wself : 0.f;
        const int start = rowptr[n], end = rowptr[n + 1];
        for (int base = start; base < end; base += 64) {
            int sl = 0;
            float wl = 0.f;
            if (base + lane < end) {
                sl = (int)ssrc[base + lane];
                wl = expc(asrc[sl] + ad);
            }
            wpart += wl;
            const int cnt = min(64, end - base);
            int j = 0;
            for (; j + 16 <= cnt; j += 16) {
                unsigned int u[16];
                float w[16];
#pragma unroll
                for (int t = 0; t < 16; t++) {
                    unsigned s = (unsigned)rdl(sl, j + t);
                    u[t] = h2[(s << 6) | ul];
                }
#pragma unroll
                for (int t = 0; t < 16; t++) w[t] = rdlf(wl, j + t);
#pragma unroll
                for (int t = 0; t < 16; t++) {
                    accx += w[t] * bflo(u[t]);
                    accy += w[t] * bfhi(u[t]);
                }
            }
            for (; j + 8 <= cnt; j += 8) {
                unsigned int u[8];
                float w[8];
#pragma unroll
                for (int t = 0; t < 8; t++) {
                    unsigned s = (unsigned)rdl(sl, j + t);
                    u[t] = h2[(s << 6) | ul];
                }
#pragma unroll
                for (int t = 0; t < 8; t++) w[t] = rdlf(wl, j + t);
#pragma unroll
                for (int t = 0; t < 8; t++) {
                    accx += w[t] * bflo(u[t]);
                    accy += w[t] * bfhi(u[t]);
                }
            }
            for (; j < cnt; j++) {
                unsigned s = (unsigned)rdl(sl, j);
                float w = rdlf(wl, j);
                unsigned int ww = h2[(s << 6) | ul];
                accx += w * bflo(ww);
                accy += w * bfhi(ww);
            }
        }
        float wsum = wpart;
#pragma unroll
        for (int o = 32; o > 0; o >>= 1) wsum += __shfl_xor(wsum, o);
        float inv = 1.f / (wsum + 1e-16f);
        float2 ov = {fmaxf(accx * inv + bx, 0.f), fmaxf(accy * inv + by, 0.f)};
        *(float2*)&feat[(size_t)n * 128 + 2 * lane] = ov;
    }
}

__global__ __launch_bounds__(256) void agg_fused5(
    const int* __restrict__ rowptr, const unsigned short* __restrict__ ssrc,
    const float* __restrict__ h3p, const float* __restrict__ asrc,
    const float* __restrict__ adst, const void* __restrict__ b3,
    const int* __restrict__ flags, float* __restrict__ out, int N)
{
    const int bf = flags[0];
    const int lane = threadIdx.x & 63;
    int wave = (blockIdx.x * 256 + threadIdx.x) >> 6;
    int nw = (gridDim.x * 256) >> 6;

    for (int n = wave; n < N; n += nw) {
        float ad = adst[n];
        float a0 = 0.f, a1 = 0.f, a2 = 0.f, a3 = 0.f, a4 = 0.f, wsum = 0.f;
        if (lane == 0) {
            float w = expc(asrc[n] + ad);
            wsum = w;
            float4 v = *(const float4*)&h3p[(unsigned)n * 8u];
            float v4 = h3p[(unsigned)n * 8u + 4u];
            a0 = w * v.x; a1 = w * v.y; a2 = w * v.z; a3 = w * v.w; a4 = w * v4;
        }
        const int start = rowptr[n], end = rowptr[n + 1];
        for (int i = start + lane; i < end; i += 64) {
            unsigned s = (unsigned)ssrc[i];
            float w = expc(asrc[s] + ad);
            float4 v = *(const float4*)&h3p[s * 8u];
            float v4 = h3p[s * 8u + 4u];
            wsum += w;
            a0 += w * v.x; a1 += w * v.y; a2 += w * v.z; a3 += w * v.w; a4 += w * v4;
        }
#pragma unroll
        for (int o = 32; o > 0; o >>= 1) {
            a0 += __shfl_xor(a0, o); a1 += __shfl_xor(a1, o); a2 += __shfl_xor(a2, o);
            a3 += __shfl_xor(a3, o); a4 += __shfl_xor(a4, o); wsum += __shfl_xor(wsum, o);
        }
        if (lane == 0) {
            float inv = 1.f / (wsum + 1e-16f);
            float v0 = a0 * inv + ldany(b3, bf, 0);
            float v1 = a1 * inv + ldany(b3, bf, 1);
            float v2 = a2 * inv + ldany(b3, bf, 2);
            float v3 = a3 * inv + ldany(b3, bf, 3);
            float v4 = a4 * inv + ldany(b3, bf, 4);
            float m = fmaxf(fmaxf(fmaxf(v0, v1), fmaxf(v2, v3)), v4);
            float s = __expf(v0 - m) + __expf(v1 - m) + __expf(v2 - m)
                    + __expf(v3 - m) + __expf(v4 - m);
            float lse = m + __logf(s);
            out[n * 5 + 0] = v0 - lse; out[n * 5 + 1] = v1 - lse;
            out[n * 5 + 2] = v2 - lse; out[n * 5 + 3] = v3 - lse;
            out[n * 5 + 4] = v4 - lse;
        }
    }
}

extern "C" void kernel_launch(void* const* d_in, const int* in_sizes, int n_in,
                              void* d_out, int out_size, void* d_ws, size_t ws_size,
                              hipStream_t stream)
{
    const void* x  = d_in[0];
    const void* ei = d_in[1];
    const void* W1 = d_in[2];
    const void* as1= d_in[3];
    const void* ad1= d_in[4];
    const void* b1 = d_in[5];
    const void* W2 = d_in[6];
    const void* as2= d_in[7];
    const void* ad2= d_in[8];
    const void* b2 = d_in[9];
    const void* W3 = d_in[10];
    const void* as3= d_in[11];
    const void* ad3= d_in[12];
    const void* b3 = d_in[13];

    const int N = in_sizes[0] / 13;      // 50000
    const int E = in_sizes[1] / 2;       // 1600000
    const int NBUK = (N + 127) / 128;    // 391

    // ws: feat(N*128 f32) | h2(N*64 u32) | asrc | adst | h3p(8N) | rowptr(N+1) |
    //     bucketBase(NBUK+1) | blockHist(256*NBUK) | W2T(128*128 u16) |
    //     pairbuf(E u32) | ssrc16(E) | flags
    float* ws    = (float*)d_ws;
    float* feat  = ws;
    unsigned int* h2 = (unsigned int*)(feat + (size_t)N * 128);
    float* asrc  = (float*)(h2 + (size_t)N * 64);
    float* adst  = asrc + N;
    float* h3p   = adst + N;
    int*   rowptr= (int*)(h3p + (size_t)N * 8);
    int*   bucketBase = rowptr + N + 1;
    int*   blockHist  = bucketBase + NBUK + 1;
    unsigned short* W2T = (unsigned short*)(blockHist + 256 * NBUK);
    unsigned int* pairbuf = (unsigned int*)(W2T + 128 * 128);
    unsigned short* ssrc16 = (unsigned short*)(pairbuf + E);
    int*   flags = (int*)(ssrc16 + E);

    const int half = N / 2;
    const int wbh = (half + 3) / 4;        // half-range agg blocks
    const int wbh2 = (N - half + 3) / 4;
    const int wb = (N + 3) / 4;
    const int gb = (N + 63) / 64;
    const int pb = (N + 255) / 256;

    detect_kernel<<<1, 64, 0, stream>>>(W1, ei, flags);

    sortA_hist<<<256, 256, 0, stream>>>(ei, flags, blockHist, E, NBUK);
    sortB_prefix<<<NBUK, 256, 0, stream>>>(blockHist, bucketBase, NBUK);
    sortB2_scan<<<1, 512, 0, stream>>>(bucketBase, NBUK);
    sortC_scatter<<<256, 256, 0, stream>>>(ei, flags, blockHist, bucketBase,
                                           pairbuf, E, NBUK);
    sortD_bin<<<NBUK, 256, 0, stream>>>(pairbuf, bucketBase, rowptr, ssrc16, N, NBUK);
    packW2T<<<128, 128, 0, stream>>>(W2, flags, W2T);

    // ---- layer 1: 13 -> 128 ----
    node_prep13<<<1024, 256, 0, stream>>>(x, W1, as1, ad1, flags, h2, asrc, adst, N);
    agg_fused128<<<wbh, 256, 0, stream>>>(rowptr, ssrc16, h2, asrc, adst, b1, flags,
                                          feat, 0, half);
    agg_fused128<<<wbh2, 256, 0, stream>>>(rowptr, ssrc16, h2, asrc, adst, b1, flags,
                                           feat, half, N);

    // ---- layer 2: 128 -> 128 (MFMA GEMM w/ fused alpha) ----
    gemm_mfma<<<gb, 256, 0, stream>>>(feat, W2T, as2, ad2, flags, h2, asrc, adst, N);
    agg_fused128<<<wbh, 256, 0, stream>>>(rowptr, ssrc16, h2, asrc, adst, b2, flags,
                                          feat, 0, half);
    agg_fused128<<<wbh2, 256, 0, stream>>>(rowptr, ssrc16, h2, asrc, adst, b2, flags,
                                           feat, half, N);

    // ---- layer 3: 128 -> 5 + log_softmax ----
    proj7<<<pb, 256, 0, stream>>>(feat, W3, as3, ad3, flags, h3p, asrc, adst, N);
    agg_fused5<<<wb, 256, 0, stream>>>(rowptr, ssrc16, h3p, asrc, adst, b3, flags,
                                       (float*)d_out, N);
}

// Round 14
// 331.608 us; speedup vs baseline: 1.0377x; 1.0377x over previous
//
#include <hip/hip_runtime.h>
#include <hip/hip_bf16.h>

// 3-layer GAT: N=50000, E=1.6M (+implicit self loops), 13->128->128->5, log_softmax.
// f32 in/out (runtime-verified), edge_index width runtime-detected.
// Round 14: proj7 -> wave-per-node (round-13 counters: 196 blocks on 256 CUs,
// Occupancy 7%, 44us pure starvation). Agg half-split kept for diagnostics.

#define LEAKY(e) ((e) > 0.f ? (e) : 0.2f * (e))
__device__ inline float clamp30(float e) { return fminf(fmaxf(e, -30.f), 30.f); }
__device__ inline float expc(float e) { return __expf(clamp30(LEAKY(e))); }

__device__ inline float ldany(const void* p, int bf, int i) {
    return bf ? __bfloat162float(((const __hip_bfloat16*)p)[i])
              : ((const float*)p)[i];
}
__device__ inline int ldidx(const void* p, int i64, long long i) {
    return i64 ? (int)(((const unsigned int*)p)[2 * i])
               : ((const int*)p)[i];
}

__device__ inline float bflo(unsigned int w) { return __uint_as_float(w << 16); }
__device__ inline float bfhi(unsigned int w) { return __uint_as_float(w & 0xffff0000u); }
__device__ inline unsigned short bfbits(float a) {
    __hip_bfloat16 x = __float2bfloat16(a);
    unsigned short u; __builtin_memcpy(&u, &x, 2); return u;
}
__device__ inline unsigned int packbf(float a, float b) {
    return (unsigned int)bfbits(a) | ((unsigned int)bfbits(b) << 16);
}

typedef __attribute__((ext_vector_type(8))) short short8;
typedef __attribute__((ext_vector_type(4))) float f32x4;

__global__ void detect_kernel(const void* W1, const void* ei, int* flags) {
    if (threadIdx.x == 0 && blockIdx.x == 0) {
        const unsigned int* w = (const unsigned int*)W1;
        int c = 0;
        for (int i = 0; i < 64; i++) {
            unsigned int e = (w[i] >> 7) & 0xFFu;
            if (e >= 0x70u && e <= 0x7Fu) c++;
        }
        flags[0] = (c >= 32) ? 1 : 0;
        const unsigned int* q = (const unsigned int*)ei;
        int z = 0;
        for (int i = 0; i < 64; i++)
            if (q[2 * i + 1] == 0u) z++;
        flags[1] = (z >= 32) ? 1 : 0;
    }
}

// ================= CSR build (contention-free chain) =================

__global__ __launch_bounds__(256) void sortA_hist(
    const void* __restrict__ ei, const int* __restrict__ flags,
    int* __restrict__ blockHist, int E, int NBUK)
{
    __shared__ int hist[512];
    const int i64 = flags[1];
    const int tid = threadIdx.x, blk = blockIdx.x;
    for (int i = tid; i < NBUK; i += 256) hist[i] = 0;
    __syncthreads();
    const int chunk = (E + 255) / 256;
    const int e0 = blk * chunk, e1 = min(e0 + chunk, E);
    for (int t = e0 + tid; t < e1; t += 256) {
        int d = ldidx(ei, i64, (long long)E + t);
        atomicAdd(&hist[d >> 7], 1);
    }
    __syncthreads();
    for (int i = tid; i < NBUK; i += 256)
        blockHist[blk * NBUK + i] = hist[i];
}

__global__ __launch_bounds__(256) void sortB_prefix(
    int* __restrict__ blockHist, int* __restrict__ bucketBase, int NBUK)
{
    __shared__ int wt[4];
    __shared__ int wbase[4];
    const int b = blockIdx.x;
    const int tid = threadIdx.x, lane = tid & 63, wid = tid >> 6;
    int v = blockHist[tid * NBUK + b];
    int x = v;
#pragma unroll
    for (int o = 1; o < 64; o <<= 1) {
        int y = __shfl_up(x, o);
        if (lane >= o) x += y;
    }
    if (lane == 63) wt[wid] = x;
    __syncthreads();
    if (tid == 0) {
        int s = 0;
#pragma unroll
        for (int i = 0; i < 4; i++) { wbase[i] = s; s += wt[i]; }
        bucketBase[b] = s;
    }
    __syncthreads();
    blockHist[tid * NBUK + b] = x - v + wbase[wid];
}

__global__ __launch_bounds__(512) void sortB2_scan(
    int* __restrict__ bucketBase, int NBUK)
{
    __shared__ int wt[8];
    __shared__ int wbase[8];
    __shared__ int total_s;
    const int tid = threadIdx.x, lane = tid & 63, wid = tid >> 6;
    int v = (tid < NBUK) ? bucketBase[tid] : 0;
    int x = v;
#pragma unroll
    for (int o = 1; o < 64; o <<= 1) {
        int y = __shfl_up(x, o);
        if (lane >= o) x += y;
    }
    if (lane == 63) wt[wid] = x;
    __syncthreads();
    if (tid == 0) {
        int s = 0;
#pragma unroll
        for (int i = 0; i < 8; i++) { wbase[i] = s; s += wt[i]; }
        total_s = s;
    }
    __syncthreads();
    if (tid < NBUK) bucketBase[tid] = x - v + wbase[wid];
    if (tid == 0) bucketBase[NBUK] = total_s;
}

__global__ __launch_bounds__(256) void sortC_scatter(
    const void* __restrict__ ei, const int* __restrict__ flags,
    const int* __restrict__ blockHist, const int* __restrict__ bucketBase,
    unsigned int* __restrict__ pairbuf, int E, int NBUK)
{
    __shared__ int cur[512];
    const int i64 = flags[1];
    const int tid = threadIdx.x, blk = blockIdx.x;
    for (int i = tid; i < NBUK; i += 256)
        cur[i] = blockHist[blk * NBUK + i] + bucketBase[i];
    __syncthreads();
    const int chunk = (E + 255) / 256;
    const int e0 = blk * chunk, e1 = min(e0 + chunk, E);
    for (int t = e0 + tid; t < e1; t += 256) {
        int s = ldidx(ei, i64, t);
        int d = ldidx(ei, i64, (long long)E + t);
        int pos = atomicAdd(&cur[d >> 7], 1);
        pairbuf[pos] = ((unsigned int)(d & 127) << 16) | (unsigned int)s;
    }
}

__global__ __launch_bounds__(256) void sortD_bin(
    const unsigned int* __restrict__ pairbuf, const int* __restrict__ bucketBase,
    int* __restrict__ rowptr, unsigned short* __restrict__ ssrc, int N, int NBUK)
{
    __shared__ int cnt[128];
    __shared__ int cur2[128];
    __shared__ int wt1;
    const int b = blockIdx.x;
    const int tid = threadIdx.x, lane = tid & 63;
    const int e0 = bucketBase[b], e1 = bucketBase[b + 1];
    if (tid < 128) cnt[tid] = 0;
    __syncthreads();
    for (int i = e0 + tid; i < e1; i += 256)
        atomicAdd(&cnt[pairbuf[i] >> 16], 1);
    __syncthreads();
    if (tid < 128) {
        int v = cnt[tid];
        int x = v;
#pragma unroll
        for (int o = 1; o < 64; o <<= 1) {
            int y = __shfl_up(x, o);
            if (lane >= o) x += y;
        }
        if (tid == 63) wt1 = x;
        __syncthreads();
        if (tid >= 64) x += wt1;
        int pfx = x - v;
        cur2[tid] = pfx;
        int node = b * 128 + tid;
        if (node < N) rowptr[node] = e0 + pfx;
    } else {
        __syncthreads();
    }
    if (b == NBUK - 1 && tid == 0) rowptr[N] = e1;
    __syncthreads();
    for (int i = e0 + tid; i < e1; i += 256) {
        unsigned int w = pairbuf[i];
        int p = atomicAdd(&cur2[w >> 16], 1);
        ssrc[e0 + p] = (unsigned short)(w & 0xFFFFu);
    }
}

// ================= projection kernels =================

__global__ __launch_bounds__(256) void node_prep13(
    const void* __restrict__ xin, const void* __restrict__ Wg,
    const void* __restrict__ asg, const void* __restrict__ adg,
    const int* __restrict__ flags,
    unsigned int* __restrict__ h2, float* __restrict__ asrc,
    float* __restrict__ adst, int N)
{
    const int bf = flags[0];
    __shared__ float Wlds[13 * 128];
    for (int i = threadIdx.x; i < 13 * 128; i += 256)
        Wlds[i] = ldany(Wg, bf, i);
    __syncthreads();
    const int lane = threadIdx.x & 63;
    int wave = (blockIdx.x * 256 + threadIdx.x) >> 6;
    int nw = (gridDim.x * 256) >> 6;
    float a0 = ldany(asg, bf, 2 * lane), a1 = ldany(asg, bf, 2 * lane + 1);
    float d0 = ldany(adg, bf, 2 * lane), d1 = ldany(adg, bf, 2 * lane + 1);
    for (int n = wave; n < N; n += nw) {
        float x0 = (lane < 13) ? ldany(xin, bf, n * 13 + lane) : 0.f;
        float s0 = 0.f, s1 = 0.f;
#pragma unroll
        for (int k = 0; k < 13; k++) {
            float xv = __shfl(x0, k);
            s0 += xv * Wlds[k * 128 + 2 * lane];
            s1 += xv * Wlds[k * 128 + 2 * lane + 1];
        }
        float pa = s0 * a0 + s1 * a1;
        float pd = s0 * d0 + s1 * d1;
#pragma unroll
        for (int o = 32; o > 0; o >>= 1) {
            pa += __shfl_xor(pa, o);
            pd += __shfl_xor(pd, o);
        }
        if (lane == 0) { asrc[n] = pa; adst[n] = pd; }
        h2[(size_t)n * 64 + lane] = packbf(s0, s1);
    }
}

// One-time: W2 -> bf16 transpose (W2T[n][k]), 32 KB.
__global__ __launch_bounds__(128) void packW2T(
    const void* __restrict__ Wg, const int* __restrict__ flags,
    unsigned short* __restrict__ W2T)
{
    const int bf = flags[0];
    const int n = blockIdx.x;
    const int k = threadIdx.x;
    W2T[n * 128 + k] = bf ? ((const unsigned short*)Wg)[k * 128 + n]
                          : bfbits(((const float*)Wg)[k * 128 + n]);
}

// Layer 2 via MFMA bf16 (layouts verified m89/m91); B staged from pre-packed W2T.
__global__ __launch_bounds__(256) void gemm_mfma(
    const float* __restrict__ X, const unsigned short* __restrict__ W2T,
    const void* __restrict__ asg, const void* __restrict__ adg,
    const int* __restrict__ flags, unsigned int* __restrict__ h2,
    float* __restrict__ asrc, float* __restrict__ adst, int N)
{
    const int bf = flags[0];
    __shared__ unsigned short A_s[64 * 136];
    __shared__ unsigned short B_s[128 * 136];
    const int tid = threadIdx.x;
    const int nb0 = blockIdx.x * 64;

#pragma unroll
    for (int it = 0; it < 8; it++) {
        int f = it * 256 + tid;
        int n = f >> 4, kc = (f & 15) * 8;
        uint4 v = *(const uint4*)&W2T[n * 128 + kc];
        *(uint4*)&B_s[n * 136 + kc] = v;
    }
#pragma unroll
    for (int it = 0; it < 8; it++) {
        int f = it * 256 + tid;
        int n = f >> 5, g = f & 31;
        int node = min(nb0 + n, N - 1);
        float4 v = *(const float4*)&X[(size_t)node * 128 + g * 4];
        unsigned int* dst = (unsigned int*)&A_s[n * 136 + g * 4];
        dst[0] = packbf(v.x, v.y);
        dst[1] = packbf(v.z, v.w);
    }
    __syncthreads();

    const int wv = tid >> 6;
    const int lane = tid & 63;
    const int m = lane & 15, quad = lane >> 4;

    f32x4 acc[8];
#pragma unroll
    for (int c = 0; c < 8; c++) acc[c] = (f32x4){0.f, 0.f, 0.f, 0.f};

#pragma unroll
    for (int q = 0; q < 4; q++) {
        short8 a = *(const short8*)&A_s[(wv * 16 + m) * 136 + q * 32 + quad * 8];
#pragma unroll
        for (int c = 0; c < 8; c++) {
            short8 b = *(const short8*)&B_s[(c * 16 + m) * 136 + q * 32 + quad * 8];
            acc[c] = __builtin_amdgcn_mfma_f32_16x16x32_bf16(a, b, acc[c], 0, 0, 0);
        }
    }

    float asv[8], adv[8];
#pragma unroll
    for (int c = 0; c < 8; c++) {
        asv[c] = ldany(asg, bf, c * 16 + m);
        adv[c] = ldany(adg, bf, c * 16 + m);
    }
    unsigned short* h2u = (unsigned short*)h2;
#pragma unroll
    for (int reg = 0; reg < 4; reg++) {
        int node = nb0 + wv * 16 + quad * 4 + reg;
        float pa = 0.f, pd = 0.f;
#pragma unroll
        for (int c = 0; c < 8; c++) {
            float v = acc[c][reg];
            pa += v * asv[c];
            pd += v * adv[c];
            if (node < N) h2u[(size_t)node * 128 + c * 16 + m] = bfbits(v);
        }
#pragma unroll
        for (int o = 1; o < 16; o <<= 1) {
            pa += __shfl_xor(pa, o);
            pd += __shfl_xor(pd, o);
        }
        if (node < N && m == 0) { asrc[node] = pa; adst[node] = pd; }
    }
}

// Layer 3: WAVE per node (fix: old thread-per-node ran only 196 blocks, 7% occ).
// WpT[j][k]: j=0..4 W3 col j, 5 = a_src3, 6 = a_dst3. Stride-1 lane access.
__global__ __launch_bounds__(256) void proj7w(
    const float* __restrict__ X, const void* __restrict__ W3,
    const void* __restrict__ as3, const void* __restrict__ ad3,
    const int* __restrict__ flags, float* __restrict__ h3p,
    float* __restrict__ asrc, float* __restrict__ adst, int N)
{
    const int bf = flags[0];
    __shared__ float WpT[7 * 128];
    const int tid = threadIdx.x;
    for (int i = tid; i < 7 * 128; i += 256) {
        int j = i >> 7, k = i & 127;
        float v;
        if (j < 5) v = ldany(W3, bf, k * 5 + j);
        else if (j == 5) v = ldany(as3, bf, k);
        else v = ldany(ad3, bf, k);
        WpT[i] = v;
    }
    __syncthreads();
    const int lane = tid & 63;
    int wave = (blockIdx.x * 256 + tid) >> 6;
    int nw = (gridDim.x * 256) >> 6;
    for (int n = wave; n < N; n += nw) {
        float x0 = X[(size_t)n * 128 + lane];
        float x1 = X[(size_t)n * 128 + 64 + lane];
        float p[7];
#pragma unroll
        for (int j = 0; j < 7; j++)
            p[j] = x0 * WpT[j * 128 + lane] + x1 * WpT[j * 128 + 64 + lane];
#pragma unroll
        for (int o = 32; o > 0; o >>= 1) {
#pragma unroll
            for (int j = 0; j < 7; j++) p[j] += __shfl_xor(p[j], o);
        }
        if (lane == 0) {
            float4 o0 = {p[0], p[1], p[2], p[3]};
            *(float4*)&h3p[(size_t)n * 8] = o0;
            h3p[(size_t)n * 8 + 4] = p[4];
            asrc[n] = p[5];
            adst[n] = p[6];
        }
    }
}

// ================= aggregation kernels =================

__device__ inline int rdl(int v, int j) { return __builtin_amdgcn_readlane(v, j); }
__device__ inline float rdlf(float v, int j) {
    return __uint_as_float((unsigned int)__builtin_amdgcn_readlane((int)__float_as_uint(v), j));
}

// Half-range dispatch: nodes [nStart, nEnd).
__global__ __launch_bounds__(256) void agg_fused128(
    const int* __restrict__ rowptr, const unsigned short* __restrict__ ssrc,
    const unsigned int* __restrict__ h2, const float* __restrict__ asrc,
    const float* __restrict__ adst, const void* __restrict__ bias,
    const int* __restrict__ flags, float* __restrict__ feat, int nStart, int nEnd)
{
    const int bf = flags[0];
    const int lane = threadIdx.x & 63;
    int wave = (blockIdx.x * 256 + threadIdx.x) >> 6;
    int nw = (gridDim.x * 256) >> 6;
    const float bx = ldany(bias, bf, 2 * lane);
    const float by = ldany(bias, bf, 2 * lane + 1);
    const unsigned ul = (unsigned)lane;

    for (int n = nStart + wave; n < nEnd; n += nw) {
        float ad = adst[n];
        float wself = expc(asrc[n] + ad);
        unsigned int hw = h2[((unsigned)n << 6) | ul];
        float accx = wself * bflo(hw), accy = wself * bfhi(hw);
        float wpart = (lane == 0) ? wself : 0.f;
        const int start = rowptr[n], end = rowptr[n + 1];
        for (int base = start; base < end; base += 64) {
            int sl = 0;
            float wl = 0.f;
            if (base + lane < end) {
                sl = (int)ssrc[base + lane];
                wl = expc(asrc[sl] + ad);
            }
            wpart += wl;
            const int cnt = min(64, end - base);
            int j = 0;
            for (; j + 16 <= cnt; j += 16) {
                unsigned int u[16];
                float w[16];
#pragma unroll
                for (int t = 0; t < 16; t++) {
                    unsigned s = (unsigned)rdl(sl, j + t);
                    u[t] = h2[(s << 6) | ul];
                }
#pragma unroll
                for (int t = 0; t < 16; t++) w[t] = rdlf(wl, j + t);
#pragma unroll
                for (int t = 0; t < 16; t++) {
                    accx += w[t] * bflo(u[t]);
                    accy += w[t] * bfhi(u[t]);
                }
            }
            for (; j + 8 <= cnt; j += 8) {
                unsigned int u[8];
                float w[8];
#pragma unroll
                for (int t = 0; t < 8; t++) {
                    unsigned s = (unsigned)rdl(sl, j + t);
                    u[t] = h2[(s << 6) | ul];
                }
#pragma unroll
                for (int t = 0; t < 8; t++) w[t] = rdlf(wl, j + t);
#pragma unroll
                for (int t = 0; t < 8; t++) {
                    accx += w[t] * bflo(u[t]);
                    accy += w[t] * bfhi(u[t]);
                }
            }
            for (; j < cnt; j++) {
                unsigned s = (unsigned)rdl(sl, j);
                float w = rdlf(wl, j);
                unsigned int ww = h2[(s << 6) | ul];
                accx += w * bflo(ww);
                accy += w * bfhi(ww);
            }
        }
        float wsum = wpart;
#pragma unroll
        for (int o = 32; o > 0; o >>= 1) wsum += __shfl_xor(wsum, o);
        float inv = 1.f / (wsum + 1e-16f);
        float2 ov = {fmaxf(accx * inv + bx, 0.f), fmaxf(accy * inv + by, 0.f)};
        *(float2*)&feat[(size_t)n * 128 + 2 * lane] = ov;
    }
}

__global__ __launch_bounds__(256) void agg_fused5(
    const int* __restrict__ rowptr, const unsigned short* __restrict__ ssrc,
    const float* __restrict__ h3p, const float* __restrict__ asrc,
    const float* __restrict__ adst, const void* __restrict__ b3,
    const int* __restrict__ flags, float* __restrict__ out, int N)
{
    const int bf = flags[0];
    const int lane = threadIdx.x & 63;
    int wave = (blockIdx.x * 256 + threadIdx.x) >> 6;
    int nw = (gridDim.x * 256) >> 6;

    for (int n = wave; n < N; n += nw) {
        float ad = adst[n];
        float a0 = 0.f, a1 = 0.f, a2 = 0.f, a3 = 0.f, a4 = 0.f, wsum = 0.f;
        if (lane == 0) {
            float w = expc(asrc[n] + ad);
            wsum = w;
            float4 v = *(const float4*)&h3p[(unsigned)n * 8u];
            float v4 = h3p[(unsigned)n * 8u + 4u];
            a0 = w * v.x; a1 = w * v.y; a2 = w * v.z; a3 = w * v.w; a4 = w * v4;
        }
        const int start = rowptr[n], end = rowptr[n + 1];
        for (int i = start + lane; i < end; i += 64) {
            unsigned s = (unsigned)ssrc[i];
            float w = expc(asrc[s] + ad);
            float4 v = *(const float4*)&h3p[s * 8u];
            float v4 = h3p[s * 8u + 4u];
            wsum += w;
            a0 += w * v.x; a1 += w * v.y; a2 += w * v.z; a3 += w * v.w; a4 += w * v4;
        }
#pragma unroll
        for (int o = 32; o > 0; o >>= 1) {
            a0 += __shfl_xor(a0, o); a1 += __shfl_xor(a1, o); a2 += __shfl_xor(a2, o);
            a3 += __shfl_xor(a3, o); a4 += __shfl_xor(a4, o); wsum += __shfl_xor(wsum, o);
        }
        if (lane == 0) {
            float inv = 1.f / (wsum + 1e-16f);
            float v0 = a0 * inv + ldany(b3, bf, 0);
            float v1 = a1 * inv + ldany(b3, bf, 1);
            float v2 = a2 * inv + ldany(b3, bf, 2);
            float v3 = a3 * inv + ldany(b3, bf, 3);
            float v4 = a4 * inv + ldany(b3, bf, 4);
            float m = fmaxf(fmaxf(fmaxf(v0, v1), fmaxf(v2, v3)), v4);
            float s = __expf(v0 - m) + __expf(v1 - m) + __expf(v2 - m)
                    + __expf(v3 - m) + __expf(v4 - m);
            float lse = m + __logf(s);
            out[n * 5 + 0] = v0 - lse; out[n * 5 + 1] = v1 - lse;
            out[n * 5 + 2] = v2 - lse; out[n * 5 + 3] = v3 - lse;
            out[n * 5 + 4] = v4 - lse;
        }
    }
}

extern "C" void kernel_launch(void* const* d_in, const int* in_sizes, int n_in,
                              void* d_out, int out_size, void* d_ws, size_t ws_size,
                              hipStream_t stream)
{
    const void* x  = d_in[0];
    const void* ei = d_in[1];
    const void* W1 = d_in[2];
    const void* as1= d_in[3];
    const void* ad1= d_in[4];
    const void* b1 = d_in[5];
    const void* W2 = d_in[6];
    const void* as2= d_in[7];
    const void* ad2= d_in[8];
    const void* b2 = d_in[9];
    const void* W3 = d_in[10];
    const void* as3= d_in[11];
    const void* ad3= d_in[12];
    const void* b3 = d_in[13];

    const int N = in_sizes[0] / 13;      // 50000
    const int E = in_sizes[1] / 2;       // 1600000
    const int NBUK = (N + 127) / 128;    // 391

    float* ws    = (float*)d_ws;
    float* feat  = ws;
    unsigned int* h2 = (unsigned int*)(feat + (size_t)N * 128);
    float* asrc  = (float*)(h2 + (size_t)N * 64);
    float* adst  = asrc + N;
    float* h3p   = adst + N;
    int*   rowptr= (int*)(h3p + (size_t)N * 8);
    int*   bucketBase = rowptr + N + 1;
    int*   blockHist  = bucketBase + NBUK + 1;
    unsigned short* W2T = (unsigned short*)(blockHist + 256 * NBUK);
    unsigned int* pairbuf = (unsigned int*)(W2T + 128 * 128);
    unsigned short* ssrc16 = (unsigned short*)(pairbuf + E);
    int*   flags = (int*)(ssrc16 + E);

    const int half = N / 2;
    const int wbh = (half + 3) / 4;
    const int wbh2 = (N - half + 3) / 4;
    const int wb = (N + 3) / 4;
    const int gb = (N + 63) / 64;

    detect_kernel<<<1, 64, 0, stream>>>(W1, ei, flags);

    sortA_hist<<<256, 256, 0, stream>>>(ei, flags, blockHist, E, NBUK);
    sortB_prefix<<<NBUK, 256, 0, stream>>>(blockHist, bucketBase, NBUK);
    sortB2_scan<<<1, 512, 0, stream>>>(bucketBase, NBUK);
    sortC_scatter<<<256, 256, 0, stream>>>(ei, flags, blockHist, bucketBase,
                                           pairbuf, E, NBUK);
    sortD_bin<<<NBUK, 256, 0, stream>>>(pairbuf, bucketBase, rowptr, ssrc16, N, NBUK);
    packW2T<<<128, 128, 0, stream>>>(W2, flags, W2T);

    // ---- layer 1: 13 -> 128 ----
    node_prep13<<<1024, 256, 0, stream>>>(x, W1, as1, ad1, flags, h2, asrc, adst, N);
    agg_fused128<<<wbh, 256, 0, stream>>>(rowptr, ssrc16, h2, asrc, adst, b1, flags,
                                          feat, 0, half);
    agg_fused128<<<wbh2, 256, 0, stream>>>(rowptr, ssrc16, h2, asrc, adst, b1, flags,
                                           feat, half, N);

    // ---- layer 2: 128 -> 128 (MFMA GEMM w/ fused alpha) ----
    gemm_mfma<<<gb, 256, 0, stream>>>(feat, W2T, as2, ad2, flags, h2, asrc, adst, N);
    agg_fused128<<<wbh, 256, 0, stream>>>(rowptr, ssrc16, h2, asrc, adst, b2, flags,
                                          feat, 0, half);
    agg_fused128<<<wbh2, 256, 0, stream>>>(rowptr, ssrc16, h2, asrc, adst, b2, flags,
                                           feat, half, N);

    // ---- layer 3: 128 -> 5 + log_softmax ----
    proj7w<<<wb, 256, 0, stream>>>(feat, W3, as3, ad3, flags, h3p, asrc, adst, N);
    agg_fused5<<<wb, 256, 0, stream>>>(rowptr, ssrc16, h3p, asrc, adst, b3, flags,
                                       (float*)d_out, N);
}

// Round 15
// 285.843 us; speedup vs baseline: 1.2038x; 1.1601x over previous
//
#include <hip/hip_runtime.h>
#include <hip/hip_bf16.h>

// 3-layer GAT: N=50000, E=1.6M (+implicit self loops), 13->128->128->5, log_softmax.
// f32 in/out (runtime-verified), edge_index width runtime-detected (per-wave ballot).
// Round 15: dispatch-count attack (15 -> 9): (1) fusedA = sortA || node_prep13 ||
// packW2T in one grid (block-role partition, disjoint data); (2) per-wave inline
// dtype detection (detect kernel + flags removed); (3) proj7w fused into the
// layer-2 agg epilogue (feat never materialized after L2; -50MB traffic).

#define LEAKY(e) ((e) > 0.f ? (e) : 0.2f * (e))
__device__ inline float clamp30(float e) { return fminf(fmaxf(e, -30.f), 30.f); }
__device__ inline float expc(float e) { return __expf(clamp30(LEAKY(e))); }

__device__ inline float ldany(const void* p, int bf, int i) {
    return bf ? __bfloat162float(((const __hip_bfloat16*)p)[i])
              : ((const float*)p)[i];
}
__device__ inline int ldidx(const void* p, int i64, long long i) {
    return i64 ? (int)(((const unsigned int*)p)[2 * i])
               : ((const int*)p)[i];
}

__device__ inline float bflo(unsigned int w) { return __uint_as_float(w << 16); }
__device__ inline float bfhi(unsigned int w) { return __uint_as_float(w & 0xffff0000u); }
__device__ inline unsigned short bfbits(float a) {
    __hip_bfloat16 x = __float2bfloat16(a);
    unsigned short u; __builtin_memcpy(&u, &x, 2); return u;
}
__device__ inline unsigned int packbf(float a, float b) {
    return (unsigned int)bfbits(a) | ((unsigned int)bfbits(b) << 16);
}

// per-wave dtype detection (uniform across the wave; 2 loads + 2 ballots)
__device__ inline int detect_bf(const void* W1) {
    int t = threadIdx.x & 63;
    unsigned int w = ((const unsigned int*)W1)[t];
    unsigned int e = (w >> 7) & 0xFFu;
    unsigned long long m = __ballot(e >= 0x70u && e <= 0x7Fu);
    return __popcll(m) >= 32;
}
__device__ inline int detect_i64(const void* ei) {
    int t = threadIdx.x & 63;
    unsigned int q = ((const unsigned int*)ei)[2 * t + 1];
    unsigned long long m = __ballot(q == 0u);
    return __popcll(m) >= 32;
}

typedef __attribute__((ext_vector_type(8))) short short8;
typedef __attribute__((ext_vector_type(4))) float f32x4;

// ============ D1: fused sortA (blk 0..255) || prep13 (256..1279) || packW2T (1280)
__global__ __launch_bounds__(256) void fusedA(
    const void* __restrict__ xin, const void* __restrict__ ei,
    const void* __restrict__ W1, const void* __restrict__ as1,
    const void* __restrict__ ad1, const void* __restrict__ W2,
    int* __restrict__ blockHist, unsigned short* __restrict__ W2T,
    unsigned int* __restrict__ h2, float* __restrict__ asrc,
    float* __restrict__ adst, int N, int E, int NBUK)
{
    __shared__ int hist[512];
    __shared__ float Wlds[13 * 128];
    const int blk = blockIdx.x;
    const int tid = threadIdx.x;

    if (blk < 256) {
        // ---- sortA_hist ----
        const int i64 = detect_i64(ei);
        for (int i = tid; i < NBUK; i += 256) hist[i] = 0;
        __syncthreads();
        const int chunk = (E + 255) / 256;
        const int e0 = blk * chunk, e1 = min(e0 + chunk, E);
        for (int t = e0 + tid; t < e1; t += 256) {
            int d = ldidx(ei, i64, (long long)E + t);
            atomicAdd(&hist[d >> 7], 1);
        }
        __syncthreads();
        for (int i = tid; i < NBUK; i += 256)
            blockHist[blk * NBUK + i] = hist[i];
    } else if (blk < 1280) {
        // ---- node_prep13 ----
        const int bf = detect_bf(W1);
        for (int i = tid; i < 13 * 128; i += 256)
            Wlds[i] = ldany(W1, bf, i);
        __syncthreads();
        const int lane = tid & 63;
        int wave = ((blk - 256) * 256 + tid) >> 6;
        const int nw = 1024 * 4;
        float a0 = ldany(as1, bf, 2 * lane), a1 = ldany(as1, bf, 2 * lane + 1);
        float d0 = ldany(ad1, bf, 2 * lane), d1 = ldany(ad1, bf, 2 * lane + 1);
        for (int n = wave; n < N; n += nw) {
            float x0 = (lane < 13) ? ldany(xin, bf, n * 13 + lane) : 0.f;
            float s0 = 0.f, s1 = 0.f;
#pragma unroll
            for (int k = 0; k < 13; k++) {
                float xv = __shfl(x0, k);
                s0 += xv * Wlds[k * 128 + 2 * lane];
                s1 += xv * Wlds[k * 128 + 2 * lane + 1];
            }
            float pa = s0 * a0 + s1 * a1;
            float pd = s0 * d0 + s1 * d1;
#pragma unroll
            for (int o = 32; o > 0; o >>= 1) {
                pa += __shfl_xor(pa, o);
                pd += __shfl_xor(pd, o);
            }
            if (lane == 0) { asrc[n] = pa; adst[n] = pd; }
            h2[(size_t)n * 64 + lane] = packbf(s0, s1);
        }
    } else {
        // ---- packW2T: W2T[n][k] = bf16(W2[k][n]) ----
        const int bf = detect_bf(W1);
        for (int i = tid; i < 128 * 128; i += 256) {
            int n = i >> 7, k = i & 127;
            W2T[i] = bf ? ((const unsigned short*)W2)[k * 128 + n]
                        : bfbits(((const float*)W2)[k * 128 + n]);
        }
    }
}

// ============ CSR build rest (contention-free chain) ============

__global__ __launch_bounds__(256) void sortB_prefix(
    int* __restrict__ blockHist, int* __restrict__ bucketBase, int NBUK)
{
    __shared__ int wt[4];
    __shared__ int wbase[4];
    const int b = blockIdx.x;
    const int tid = threadIdx.x, lane = tid & 63, wid = tid >> 6;
    int v = blockHist[tid * NBUK + b];
    int x = v;
#pragma unroll
    for (int o = 1; o < 64; o <<= 1) {
        int y = __shfl_up(x, o);
        if (lane >= o) x += y;
    }
    if (lane == 63) wt[wid] = x;
    __syncthreads();
    if (tid == 0) {
        int s = 0;
#pragma unroll
        for (int i = 0; i < 4; i++) { wbase[i] = s; s += wt[i]; }
        bucketBase[b] = s;
    }
    __syncthreads();
    blockHist[tid * NBUK + b] = x - v + wbase[wid];
}

__global__ __launch_bounds__(512) void sortB2_scan(
    int* __restrict__ bucketBase, int NBUK)
{
    __shared__ int wt[8];
    __shared__ int wbase[8];
    __shared__ int total_s;
    const int tid = threadIdx.x, lane = tid & 63, wid = tid >> 6;
    int v = (tid < NBUK) ? bucketBase[tid] : 0;
    int x = v;
#pragma unroll
    for (int o = 1; o < 64; o <<= 1) {
        int y = __shfl_up(x, o);
        if (lane >= o) x += y;
    }
    if (lane == 63) wt[wid] = x;
    __syncthreads();
    if (tid == 0) {
        int s = 0;
#pragma unroll
        for (int i = 0; i < 8; i++) { wbase[i] = s; s += wt[i]; }
        total_s = s;
    }
    __syncthreads();
    if (tid < NBUK) bucketBase[tid] = x - v + wbase[wid];
    if (tid == 0) bucketBase[NBUK] = total_s;
}

__global__ __launch_bounds__(256) void sortC_scatter(
    const void* __restrict__ ei,
    const int* __restrict__ blockHist, const int* __restrict__ bucketBase,
    unsigned int* __restrict__ pairbuf, int E, int NBUK)
{
    __shared__ int cur[512];
    const int i64 = detect_i64(ei);
    const int tid = threadIdx.x, blk = blockIdx.x;
    for (int i = tid; i < NBUK; i += 256)
        cur[i] = blockHist[blk * NBUK + i] + bucketBase[i];
    __syncthreads();
    const int chunk = (E + 255) / 256;
    const int e0 = blk * chunk, e1 = min(e0 + chunk, E);
    for (int t = e0 + tid; t < e1; t += 256) {
        int s = ldidx(ei, i64, t);
        int d = ldidx(ei, i64, (long long)E + t);
        int pos = atomicAdd(&cur[d >> 7], 1);
        pairbuf[pos] = ((unsigned int)(d & 127) << 16) | (unsigned int)s;
    }
}

__global__ __launch_bounds__(256) void sortD_bin(
    const unsigned int* __restrict__ pairbuf, const int* __restrict__ bucketBase,
    int* __restrict__ rowptr, unsigned short* __restrict__ ssrc, int N, int NBUK)
{
    __shared__ int cnt[128];
    __shared__ int cur2[128];
    __shared__ int wt1;
    const int b = blockIdx.x;
    const int tid = threadIdx.x, lane = tid & 63;
    const int e0 = bucketBase[b], e1 = bucketBase[b + 1];
    if (tid < 128) cnt[tid] = 0;
    __syncthreads();
    for (int i = e0 + tid; i < e1; i += 256)
        atomicAdd(&cnt[pairbuf[i] >> 16], 1);
    __syncthreads();
    if (tid < 128) {
        int v = cnt[tid];
        int x = v;
#pragma unroll
        for (int o = 1; o < 64; o <<= 1) {
            int y = __shfl_up(x, o);
            if (lane >= o) x += y;
        }
        if (tid == 63) wt1 = x;
        __syncthreads();
        if (tid >= 64) x += wt1;
        int pfx = x - v;
        cur2[tid] = pfx;
        int node = b * 128 + tid;
        if (node < N) rowptr[node] = e0 + pfx;
    } else {
        __syncthreads();
    }
    if (b == NBUK - 1 && tid == 0) rowptr[N] = e1;
    __syncthreads();
    for (int i = e0 + tid; i < e1; i += 256) {
        unsigned int w = pairbuf[i];
        int p = atomicAdd(&cur2[w >> 16], 1);
        ssrc[e0 + p] = (unsigned short)(w & 0xFFFFu);
    }
}

// ============ layer-2 GEMM (MFMA, layouts verified m89/m91) ============
__global__ __launch_bounds__(256) void gemm_mfma(
    const float* __restrict__ X, const unsigned short* __restrict__ W2T,
    const void* __restrict__ asg, const void* __restrict__ adg,
    const void* __restrict__ dref, unsigned int* __restrict__ h2,
    float* __restrict__ asrc, float* __restrict__ adst, int N)
{
    const int bf = detect_bf(dref);
    __shared__ unsigned short A_s[64 * 136];
    __shared__ unsigned short B_s[128 * 136];
    const int tid = threadIdx.x;
    const int nb0 = blockIdx.x * 64;

#pragma unroll
    for (int it = 0; it < 8; it++) {
        int f = it * 256 + tid;
        int n = f >> 4, kc = (f & 15) * 8;
        uint4 v = *(const uint4*)&W2T[n * 128 + kc];
        *(uint4*)&B_s[n * 136 + kc] = v;
    }
#pragma unroll
    for (int it = 0; it < 8; it++) {
        int f = it * 256 + tid;
        int n = f >> 5, g = f & 31;
        int node = min(nb0 + n, N - 1);
        float4 v = *(const float4*)&X[(size_t)node * 128 + g * 4];
        unsigned int* dst = (unsigned int*)&A_s[n * 136 + g * 4];
        dst[0] = packbf(v.x, v.y);
        dst[1] = packbf(v.z, v.w);
    }
    __syncthreads();

    const int wv = tid >> 6;
    const int lane = tid & 63;
    const int m = lane & 15, quad = lane >> 4;

    f32x4 acc[8];
#pragma unroll
    for (int c = 0; c < 8; c++) acc[c] = (f32x4){0.f, 0.f, 0.f, 0.f};

#pragma unroll
    for (int q = 0; q < 4; q++) {
        short8 a = *(const short8*)&A_s[(wv * 16 + m) * 136 + q * 32 + quad * 8];
#pragma unroll
        for (int c = 0; c < 8; c++) {
            short8 b = *(const short8*)&B_s[(c * 16 + m) * 136 + q * 32 + quad * 8];
            acc[c] = __builtin_amdgcn_mfma_f32_16x16x32_bf16(a, b, acc[c], 0, 0, 0);
        }
    }

    float asv[8], adv[8];
#pragma unroll
    for (int c = 0; c < 8; c++) {
        asv[c] = ldany(asg, bf, c * 16 + m);
        adv[c] = ldany(adg, bf, c * 16 + m);
    }
    unsigned short* h2u = (unsigned short*)h2;
#pragma unroll
    for (int reg = 0; reg < 4; reg++) {
        int node = nb0 + wv * 16 + quad * 4 + reg;
        float pa = 0.f, pd = 0.f;
#pragma unroll
        for (int c = 0; c < 8; c++) {
            float v = acc[c][reg];
            pa += v * asv[c];
            pd += v * adv[c];
            if (node < N) h2u[(size_t)node * 128 + c * 16 + m] = bfbits(v);
        }
#pragma unroll
        for (int o = 1; o < 16; o <<= 1) {
            pa += __shfl_xor(pa, o);
            pd += __shfl_xor(pd, o);
        }
        if (node < N && m == 0) { asrc[node] = pa; adst[node] = pd; }
    }
}

// ============ aggregation ============

__device__ inline int rdl(int v, int j) { return __builtin_amdgcn_readlane(v, j); }
__device__ inline float rdlf(float v, int j) {
    return __uint_as_float((unsigned int)__builtin_amdgcn_readlane((int)__float_as_uint(v), j));
}

// core agg body: computes node n's normalized feature pair into ov
__device__ inline float2 agg_node(
    int n, const int* rowptr, const unsigned short* ssrc,
    const unsigned int* h2, const float* asrc, const float* adst,
    float bx, float by, unsigned ul)
{
    const int lane = (int)ul;
    float ad = adst[n];
    float wself = expc(asrc[n] + ad);
    unsigned int hw = h2[((unsigned)n << 6) | ul];
    float accx = wself * bflo(hw), accy = wself * bfhi(hw);
    float wpart = (lane == 0) ? wself : 0.f;
    const int start = rowptr[n], end = rowptr[n + 1];
    for (int base = start; base < end; base += 64) {
        int sl = 0;
        float wl = 0.f;
        if (base + lane < end) {
            sl = (int)ssrc[base + lane];
            wl = expc(asrc[sl] + ad);
        }
        wpart += wl;
        const int cnt = min(64, end - base);
        int j = 0;
        for (; j + 16 <= cnt; j += 16) {
            unsigned int u[16];
            float w[16];
#pragma unroll
            for (int t = 0; t < 16; t++) {
                unsigned s = (unsigned)rdl(sl, j + t);
                u[t] = h2[(s << 6) | ul];
            }
#pragma unroll
            for (int t = 0; t < 16; t++) w[t] = rdlf(wl, j + t);
#pragma unroll
            for (int t = 0; t < 16; t++) {
                accx += w[t] * bflo(u[t]);
                accy += w[t] * bfhi(u[t]);
            }
        }
        for (; j + 8 <= cnt; j += 8) {
            unsigned int u[8];
            float w[8];
#pragma unroll
            for (int t = 0; t < 8; t++) {
                unsigned s = (unsigned)rdl(sl, j + t);
                u[t] = h2[(s << 6) | ul];
            }
#pragma unroll
            for (int t = 0; t < 8; t++) w[t] = rdlf(wl, j + t);
#pragma unroll
            for (int t = 0; t < 8; t++) {
                accx += w[t] * bflo(u[t]);
                accy += w[t] * bfhi(u[t]);
            }
        }
        for (; j < cnt; j++) {
            unsigned s = (unsigned)rdl(sl, j);
            float w = rdlf(wl, j);
            unsigned int ww = h2[(s << 6) | ul];
            accx += w * bflo(ww);
            accy += w * bfhi(ww);
        }
    }
    float wsum = wpart;
#pragma unroll
    for (int o = 32; o > 0; o >>= 1) wsum += __shfl_xor(wsum, o);
    float inv = 1.f / (wsum + 1e-16f);
    float2 ov = {fmaxf(accx * inv + bx, 0.f), fmaxf(accy * inv + by, 0.f)};
    return ov;
}

// layer-1 agg: writes feat
__global__ __launch_bounds__(256) void agg_fused128(
    const int* __restrict__ rowptr, const unsigned short* __restrict__ ssrc,
    const unsigned int* __restrict__ h2, const float* __restrict__ asrc,
    const float* __restrict__ adst, const void* __restrict__ bias,
    const void* __restrict__ dref, float* __restrict__ feat, int N)
{
    const int bf = detect_bf(dref);
    const int lane = threadIdx.x & 63;
    int wave = (blockIdx.x * 256 + threadIdx.x) >> 6;
    int nw = (gridDim.x * 256) >> 6;
    const float bx = ldany(bias, bf, 2 * lane);
    const float by = ldany(bias, bf, 2 * lane + 1);
    const unsigned ul = (unsigned)lane;
    for (int n = wave; n < N; n += nw) {
        float2 ov = agg_node(n, rowptr, ssrc, h2, asrc, adst, bx, by, ul);
        *(float2*)&feat[(size_t)n * 128 + 2 * lane] = ov;
    }
}

// layer-2 agg with fused layer-3 projection: no feat write, outputs h3p + alpha3.
__global__ __launch_bounds__(256) void agg_fused128_proj(
    const int* __restrict__ rowptr, const unsigned short* __restrict__ ssrc,
    const unsigned int* __restrict__ h2, const float* __restrict__ asrc,
    const float* __restrict__ adst, const void* __restrict__ bias,
    const void* __restrict__ dref,
    const void* __restrict__ W3, const void* __restrict__ as3,
    const void* __restrict__ ad3,
    float* __restrict__ h3p, float* __restrict__ asrc3, float* __restrict__ adst3,
    int N)
{
    const int bf = detect_bf(dref);
    __shared__ float WpT[7 * 128];   // [j][feature], j: 0..4 = W3 cols, 5/6 = a3
    const int tid = threadIdx.x;
    for (int i = tid; i < 7 * 128; i += 256) {
        int j = i >> 7, k = i & 127;
        float v;
        if (j < 5) v = ldany(W3, bf, k * 5 + j);
        else if (j == 5) v = ldany(as3, bf, k);
        else v = ldany(ad3, bf, k);
        WpT[i] = v;
    }
    __syncthreads();
    const int lane = tid & 63;
    int wave = (blockIdx.x * 256 + tid) >> 6;
    int nw = (gridDim.x * 256) >> 6;
    const float bx = ldany(bias, bf, 2 * lane);
    const float by = ldany(bias, bf, 2 * lane + 1);
    const unsigned ul = (unsigned)lane;
    for (int n = wave; n < N; n += nw) {
        float2 ov = agg_node(n, rowptr, ssrc, h2, asrc, adst, bx, by, ul);
        float p[7];
#pragma unroll
        for (int j = 0; j < 7; j++)
            p[j] = ov.x * WpT[j * 128 + 2 * lane] + ov.y * WpT[j * 128 + 2 * lane + 1];
#pragma unroll
        for (int o = 32; o > 0; o >>= 1) {
#pragma unroll
            for (int j = 0; j < 7; j++) p[j] += __shfl_xor(p[j], o);
        }
        if (lane == 0) {
            float4 o0 = {p[0], p[1], p[2], p[3]};
            *(float4*)&h3p[(size_t)n * 8] = o0;
            h3p[(size_t)n * 8 + 4] = p[4];
            asrc3[n] = p[5];
            adst3[n] = p[6];
        }
    }
}

__global__ __launch_bounds__(256) void agg_fused5(
    const int* __restrict__ rowptr, const unsigned short* __restrict__ ssrc,
    const float* __restrict__ h3p, const float* __restrict__ asrc,
    const float* __restrict__ adst, const void* __restrict__ b3,
    const void* __restrict__ dref, float* __restrict__ out, int N)
{
    const int bf = detect_bf(dref);
    const int lane = threadIdx.x & 63;
    int wave = (blockIdx.x * 256 + threadIdx.x) >> 6;
    int nw = (gridDim.x * 256) >> 6;

    for (int n = wave; n < N; n += nw) {
        float ad = adst[n];
        float a0 = 0.f, a1 = 0.f, a2 = 0.f, a3 = 0.f, a4 = 0.f, wsum = 0.f;
        if (lane == 0) {
            float w = expc(asrc[n] + ad);
            wsum = w;
            float4 v = *(const float4*)&h3p[(unsigned)n * 8u];
            float v4 = h3p[(unsigned)n * 8u + 4u];
            a0 = w * v.x; a1 = w * v.y; a2 = w * v.z; a3 = w * v.w; a4 = w * v4;
        }
        const int start = rowptr[n], end = rowptr[n + 1];
        for (int i = start + lane; i < end; i += 64) {
            unsigned s = (unsigned)ssrc[i];
            float w = expc(asrc[s] + ad);
            float4 v = *(const float4*)&h3p[s * 8u];
            float v4 = h3p[s * 8u + 4u];
            wsum += w;
            a0 += w * v.x; a1 += w * v.y; a2 += w * v.z; a3 += w * v.w; a4 += w * v4;
        }
#pragma unroll
        for (int o = 32; o > 0; o >>= 1) {
            a0 += __shfl_xor(a0, o); a1 += __shfl_xor(a1, o); a2 += __shfl_xor(a2, o);
            a3 += __shfl_xor(a3, o); a4 += __shfl_xor(a4, o); wsum += __shfl_xor(wsum, o);
        }
        if (lane == 0) {
            float inv = 1.f / (wsum + 1e-16f);
            float v0 = a0 * inv + ldany(b3, bf, 0);
            float v1 = a1 * inv + ldany(b3, bf, 1);
            float v2 = a2 * inv + ldany(b3, bf, 2);
            float v3 = a3 * inv + ldany(b3, bf, 3);
            float v4 = a4 * inv + ldany(b3, bf, 4);
            float m = fmaxf(fmaxf(fmaxf(v0, v1), fmaxf(v2, v3)), v4);
            float s = __expf(v0 - m) + __expf(v1 - m) + __expf(v2 - m)
                    + __expf(v3 - m) + __expf(v4 - m);
            float lse = m + __logf(s);
            out[n * 5 + 0] = v0 - lse; out[n * 5 + 1] = v1 - lse;
            out[n * 5 + 2] = v2 - lse; out[n * 5 + 3] = v3 - lse;
            out[n * 5 + 4] = v4 - lse;
        }
    }
}

extern "C" void kernel_launch(void* const* d_in, const int* in_sizes, int n_in,
                              void* d_out, int out_size, void* d_ws, size_t ws_size,
                              hipStream_t stream)
{
    const void* x  = d_in[0];
    const void* ei = d_in[1];
    const void* W1 = d_in[2];
    const void* as1= d_in[3];
    const void* ad1= d_in[4];
    const void* b1 = d_in[5];
    const void* W2 = d_in[6];
    const void* as2= d_in[7];
    const void* ad2= d_in[8];
    const void* b2 = d_in[9];
    const void* W3 = d_in[10];
    const void* as3= d_in[11];
    const void* ad3= d_in[12];
    const void* b3 = d_in[13];

    const int N = in_sizes[0] / 13;      // 50000
    const int E = in_sizes[1] / 2;       // 1600000
    const int NBUK = (N + 127) / 128;    // 391

    // ws: feat(N*128) | h2(N*64 u32) | asrc | adst | asrc3 | adst3 | h3p(8N) |
    //     rowptr(N+1) | bucketBase(NBUK+1) | blockHist(256*NBUK) |
    //     W2T(128*128 u16) | pairbuf(E u32) | ssrc16(E)
    float* ws    = (float*)d_ws;
    float* feat  = ws;
    unsigned int* h2 = (unsigned int*)(feat + (size_t)N * 128);
    float* asrc  = (float*)(h2 + (size_t)N * 64);
    float* adst  = asrc + N;
    float* asrc3 = adst + N;
    float* adst3 = asrc3 + N;
    float* h3p   = adst3 + N;
    int*   rowptr= (int*)(h3p + (size_t)N * 8);
    int*   bucketBase = rowptr + N + 1;
    int*   blockHist  = bucketBase + NBUK + 1;
    unsigned short* W2T = (unsigned short*)(blockHist + 256 * NBUK);
    unsigned int* pairbuf = (unsigned int*)(W2T + 128 * 128);
    unsigned short* ssrc16 = (unsigned short*)(pairbuf + E);

    const int wb = (N + 3) / 4;
    const int gb = (N + 63) / 64;

    // D1: sortA || prep13 || packW2T
    fusedA<<<1281, 256, 0, stream>>>(x, ei, W1, as1, ad1, W2,
                                     blockHist, W2T, h2, asrc, adst, N, E, NBUK);
    sortB_prefix<<<NBUK, 256, 0, stream>>>(blockHist, bucketBase, NBUK);
    sortB2_scan<<<1, 512, 0, stream>>>(bucketBase, NBUK);
    sortC_scatter<<<256, 256, 0, stream>>>(ei, blockHist, bucketBase, pairbuf, E, NBUK);
    sortD_bin<<<NBUK, 256, 0, stream>>>(pairbuf, bucketBase, rowptr, ssrc16, N, NBUK);

    // layer 1 aggregate -> feat
    agg_fused128<<<wb, 256, 0, stream>>>(rowptr, ssrc16, h2, asrc, adst, b1, W1,
                                         feat, N);
    // layer 2 project (MFMA) -> h2, alpha2
    gemm_mfma<<<gb, 256, 0, stream>>>(feat, W2T, as2, ad2, W1, h2, asrc, adst, N);
    // layer 2 aggregate + fused layer-3 projection -> h3p, alpha3
    agg_fused128_proj<<<wb, 256, 0, stream>>>(rowptr, ssrc16, h2, asrc, adst, b2, W1,
                                              W3, as3, ad3, h3p, asrc3, adst3, N);
    // layer 3 aggregate + log_softmax -> out
    agg_fused5<<<wb, 256, 0, stream>>>(rowptr, ssrc16, h3p, asrc3, adst3, b3, W1,
                                       (float*)d_out, N);
}